// Round 12
// baseline (180.354 us; speedup 1.0000x reference)
//
#include <hip/hip_runtime.h>
#include <hip/hip_bf16.h>
#include <stdint.h>

// Problem dims (fixed)
#define B_  4
#define T_  2048
#define D_  1024
#define H_  16
#define DH_ 64

typedef _Float16 half8 __attribute__((ext_vector_type(8)));
typedef _Float16 half4 __attribute__((ext_vector_type(4)));
typedef __fp16   fp16x2 __attribute__((ext_vector_type(2)));
typedef float    f32x4 __attribute__((ext_vector_type(4)));

#define MFMA16(a, b, c) __builtin_amdgcn_mfma_f32_16x16x32_f16(a, b, c, 0, 0, 0)

__device__ static inline void gload_lds16(const void* g, void* l) {
  __builtin_amdgcn_global_load_lds(
      (const __attribute__((address_space(1))) void*)g,
      (__attribute__((address_space(3))) void*)l, 16, 0, 0);
}

// ---------------- convert fp32 -> fp16 (vectorized) ----------------
__global__ void convert_f32_f16(const float* __restrict__ in, _Float16* __restrict__ out, long n) {
  long i = ((long)blockIdx.x * blockDim.x + threadIdx.x) * 4;
  long stride = (long)gridDim.x * blockDim.x * 4;
  for (; i < n; i += stride) {
    float4 v = *(const float4*)(in + i);
    half4 hv;
    hv.x = (_Float16)v.x; hv.y = (_Float16)v.y; hv.z = (_Float16)v.z; hv.w = (_Float16)v.w;
    *(half4*)(out + i) = hv;
  }
}

// mask -> fp16 {0,1}
__global__ void make_maskh(const int* __restrict__ mask, _Float16* __restrict__ mh, int n) {
  int i = blockIdx.x * blockDim.x + threadIdx.x;
  if (i < n) mh[i] = mask[i] ? (_Float16)1.0f : (_Float16)0.0f;
}

// ------------- transpose+convert: in fp32 [K][N] -> out fp16 [N][K] -------------
__global__ void transpose_f32_f16(const float* __restrict__ in, _Float16* __restrict__ out,
                                  int K, int N) {
  __shared__ float tile[32][33];
  int n0 = blockIdx.x * 32, k0 = blockIdx.y * 32;
  int x = threadIdx.x, y = threadIdx.y;   // 32 x 8
  #pragma unroll
  for (int j = 0; j < 32; j += 8)
    tile[y + j][x] = in[(long)(k0 + y + j) * N + n0 + x];
  __syncthreads();
  #pragma unroll
  for (int j = 0; j < 32; j += 8)
    out[(long)(n0 + y + j) * K + k0 + x] = (_Float16)tile[x][y + j];
}

// ------------- 8-phase 256x256 GEMM for the qkv projection -------------
// C[M,N] = A[M,K] @ Bt[N,K]^T + bias, fused epilogue:
//   Q (cols 0-1023, pre-scaled 0.125*log2e) and K (1024-2047) scattered to
//   [B,H,T,DH] fp16; V (2048-3071) transposed via LDS to [bh][dh][t], masked.
// 512 thr = 8 waves (2M x 4N), wave tile 128x64, acc[8][4]. BK=64, 2 LDS
// slots/operand (128 KiB). 8 phases/iter = 4 quadrants x 2 K-tiles; raw
// s_barrier (no implicit vmcnt drain); vmcnt(0) only at PH4/PH8, issued
// 2-3 phases after the last stage; setprio around MFMA clusters (T5).
__global__ __launch_bounds__(512)
void mha_gemm8(const _Float16* __restrict__ A, const _Float16* __restrict__ Bt,
               const float* __restrict__ bias, const _Float16* __restrict__ mhp,
               _Float16* __restrict__ qo, _Float16* __restrict__ ko,
               _Float16* __restrict__ vo) {
  __shared__ _Float16 shbuf[65536];           // A: [2][16384] | B: +32768 [2][16384]
  const int tid = threadIdx.x;
  const int l = tid & 63, w = tid >> 6;       // 8 waves
  const int wm = w >> 2, wn = w & 3;
  const int hi = l >> 4, q = l & 15;
  const int K = D_;

  // bijective XCD swizzle (384 % 8 == 0)
  const int cpx = gridDim.x >> 3;
  const int wg = (blockIdx.x & 7) * cpx + (blockIdx.x >> 3);
  const int m0 = (wg / 12) * 256, n0 = (wg % 12) * 256;
  const int bb = m0 >> 11, m0t = m0 & 2047;

  // staging: chunk c = j*512 + tid -> row c>>3, granule c&7 (16B), src pre-XOR'd
  const int srow = tid >> 3, ssub = tid & 7;
  const int ssw = ssub ^ (srow & 7);
  const _Float16* a0 = A  + (long)(m0 + srow) * K + ssw * 8;
  const _Float16* b0 = Bt + (long)(n0 + srow) * K + ssw * 8;
  _Float16* lA = shbuf + tid * 8;
  _Float16* lB = shbuf + 32768 + tid * 8;
  const long joff = (long)64 * K;             // j advances 64 rows

#define STG_A(S, T) do { _Pragma("unroll")                                   \
    for (int j = 0; j < 4; ++j)                                              \
      gload_lds16(a0 + (T) * 64 + j * joff, lA + (S) * 16384 + j * 4096);    \
  } while (0)
#define STG_B(S, T) do { _Pragma("unroll")                                   \
    for (int j = 0; j < 4; ++j)                                              \
      gload_lds16(b0 + (T) * 64 + j * joff, lB + (S) * 16384 + j * 4096);    \
  } while (0)

  f32x4 acc[8][4];
  #pragma unroll
  for (int f = 0; f < 8; ++f)
    #pragma unroll
    for (int g = 0; g < 4; ++g) acc[f][g] = (f32x4){0.f, 0.f, 0.f, 0.f};

  const char* const Abase = (const char*)shbuf;
  const char* const Bbase = (const char*)shbuf + 65536;

  // prologue: stage tile 0 -> slot 0, drain, barrier
  STG_A(0, 0); STG_B(0, 0);
  asm volatile("s_waitcnt vmcnt(0)" ::: "memory");
  asm volatile("s_barrier" ::: "memory");

  half8 bf[2][4];

#define PHASE(S, QD, STG_STMT, DO_WAIT) do {                                 \
    if ((QD) == 0) {                                                         \
      _Pragma("unroll")                                                      \
      for (int g = 0; g < 4; ++g) {                                          \
        int rb = wn * 64 + g * 16 + q;                                       \
        _Pragma("unroll")                                                    \
        for (int kk = 0; kk < 2; ++kk)                                       \
          bf[kk][g] = *(const half8*)(Bbase + (S) * 32768 + rb * 128 +       \
                                      ((((kk << 2) | hi) ^ (rb & 7)) << 4)); \
      }                                                                      \
    }                                                                        \
    half8 af[2][2];                                                          \
    _Pragma("unroll")                                                        \
    for (int f2 = 0; f2 < 2; ++f2) {                                         \
      int ra = wm * 128 + ((QD) * 2 + f2) * 16 + q;                          \
      _Pragma("unroll")                                                      \
      for (int kk = 0; kk < 2; ++kk)                                         \
        af[kk][f2] = *(const half8*)(Abase + (S) * 32768 + ra * 128 +        \
                                     ((((kk << 2) | hi) ^ (ra & 7)) << 4));  \
    }                                                                        \
    STG_STMT;                                                                \
    asm volatile("s_barrier" ::: "memory");                                  \
    __builtin_amdgcn_s_setprio(1);                                           \
    _Pragma("unroll")                                                        \
    for (int kk = 0; kk < 2; ++kk)                                           \
      _Pragma("unroll")                                                      \
      for (int f2 = 0; f2 < 2; ++f2)                                         \
        _Pragma("unroll")                                                    \
        for (int g = 0; g < 4; ++g)                                          \
          acc[(QD) * 2 + f2][g] =                                            \
              MFMA16(af[kk][f2], bf[kk][g], acc[(QD) * 2 + f2][g]);          \
    __builtin_amdgcn_s_setprio(0);                                           \
    if (DO_WAIT) asm volatile("s_waitcnt vmcnt(0)" ::: "memory");            \
    asm volatile("s_barrier" ::: "memory");                                  \
  } while (0)

  for (int i = 0; i < 8; ++i) {
    const int t1 = 2 * i + 1, t2 = 2 * i + 2;
    // phases 1-4: compute slot0 (tile 2i); stage tile 2i+1 -> slot1 in PH1-2
    PHASE(0, 0, STG_A(1, t1), 0);
    PHASE(0, 1, STG_B(1, t1), 0);
    PHASE(0, 2, (void)0, 0);
    PHASE(0, 3, (void)0, 1);          // gate slot1 reads
    // phases 5-8: compute slot1 (tile 2i+1); stage tile 2i+2 -> slot0 in PH5-6
    PHASE(1, 0, if (i < 7) STG_A(0, t2), 0);
    PHASE(1, 1, if (i < 7) STG_B(0, t2), 0);
    PHASE(1, 2, (void)0, 0);
    PHASE(1, 3, (void)0, 1);          // gate next-iter slot0 reads
  }
#undef PHASE
#undef STG_A
#undef STG_B

  // ---------------- fused epilogue ----------------
  if (n0 >= 2 * D_) {
    // V tile: LDS transpose (128 KiB buffer reused) -> coalesced [bh][dh][t]
    #pragma unroll
    for (int g = 0; g < 4; ++g) {
      int colL = wn * 64 + g * 16 + q;               // 0..255
      float bv = bias[n0 + colL];
      int swz = (colL & 7) << 3;                     // XOR on row index (x8 f16)
      #pragma unroll
      for (int fr = 0; fr < 8; ++fr) {
        int rowL = wm * 128 + fr * 16 + hi * 4;
        half4 hv;
        #pragma unroll
        for (int r = 0; r < 4; ++r) {
          float mv = (float)mhp[bb * T_ + m0t + rowL + r];
          hv[r] = (_Float16)((acc[fr][g][r] + bv) * mv);
        }
        *(half4*)&shbuf[colL * 256 + (rowL ^ swz)] = hv;
      }
    }
    __syncthreads();
    #pragma unroll
    for (int it = 0; it < 16; ++it) {
      int e = it * 512 + tid;
      int colL = e >> 5, chunk = e & 31;
      int swz = (colL & 7) << 3;
      half8 v8 = *(const half8*)&shbuf[colL * 256 + ((chunk * 8) ^ swz)];
      int d = (n0 + colL) & 1023;
      int h2 = d >> 6, dh = d & 63;
      *(half8*)&vo[(((long)bb * H_ + h2) * DH_ + dh) * T_ + m0t + chunk * 8] = v8;
    }
  } else {
    #pragma unroll
    for (int g = 0; g < 4; ++g) {
      int j = n0 + wn * 64 + g * 16 + q;
      float bv = bias[j];
      int which = j >> 10;                            // uniform per block
      int d = j & 1023;
      int h = d >> 6, dh = d & 63;
      _Float16* base = which == 0 ? qo : ko;
      float sc = which == 0 ? 0.1803368801f : 1.0f;   // 0.125 * log2(e) for Q
      #pragma unroll
      for (int fr = 0; fr < 8; ++fr) {
        int rowL = m0t + wm * 128 + fr * 16 + hi * 4;
        #pragma unroll
        for (int r = 0; r < 4; ++r)
          base[(((long)bb * H_ + h) * T_ + rowL + r) * DH_ + dh] =
              (_Float16)((acc[fr][g][r] + bv) * sc);
      }
    }
  }
}

// ---------------- GEMM v2 (2-phase 128²): out-projection ----------------
__global__ __launch_bounds__(256, 2)
void mha_gemm_out(const _Float16* __restrict__ A, const _Float16* __restrict__ Bt,
                  const float* __restrict__ bias, float* __restrict__ co,
                  int M, int N, int K, int gx) {
  __shared__ _Float16 As[128 * 64];
  __shared__ _Float16 Bs[128 * 64];
  const int t = threadIdx.x;
  const int l = t & 63;
  const int w = t >> 6;
  const int wr = w >> 1, wc = w & 1;

  const int cpx = gridDim.x >> 3;
  const int wg = (blockIdx.x & 7) * cpx + (blockIdx.x >> 3);
  const int m0 = (wg / gx) * 128, n0 = (wg % gx) * 128;

  const _Float16* ag[4];
  const _Float16* bg[4];
  #pragma unroll
  for (int j = 0; j < 4; ++j) {
    int c = j * 256 + t;
    int row = c >> 3, sub = c & 7;
    int s = (sub ^ (row & 7)) * 8;
    ag[j] = A  + (long)(m0 + row) * K + s;
    bg[j] = Bt + (long)(n0 + row) * K + s;
  }

  f32x4 acc[4][4];
  #pragma unroll
  for (int f = 0; f < 4; ++f)
    #pragma unroll
    for (int g = 0; g < 4; ++g) acc[f][g] = (f32x4){0.f, 0.f, 0.f, 0.f};

  const int hi = l >> 4;

  for (int k0 = 0; k0 < K; k0 += 64) {
    #pragma unroll
    for (int j = 0; j < 4; ++j) {
      gload_lds16(ag[j] + k0, &As[j * 2048 + w * 512]);
      gload_lds16(bg[j] + k0, &Bs[j * 2048 + w * 512]);
    }
    __syncthreads();
    half8 af[2][4], bf[2][4];
    #pragma unroll
    for (int kk = 0; kk < 2; ++kk)
      #pragma unroll
      for (int f = 0; f < 4; ++f) {
        int ra = wr * 64 + f * 16 + (l & 15);
        int rb = wc * 64 + f * 16 + (l & 15);
        af[kk][f] = *(const half8*)((const char*)As + ra * 128 +
                                    ((((kk << 2) | hi) ^ (ra & 7)) << 4));
        bf[kk][f] = *(const half8*)((const char*)Bs + rb * 128 +
                                    ((((kk << 2) | hi) ^ (rb & 7)) << 4));
      }
    #pragma unroll
    for (int kk = 0; kk < 2; ++kk)
      #pragma unroll
      for (int f = 0; f < 4; ++f)
        #pragma unroll
        for (int g = 0; g < 4; ++g)
          acc[f][g] = MFMA16(af[kk][f], bf[kk][g], acc[f][g]);
    __syncthreads();
  }

  #pragma unroll
  for (int g = 0; g < 4; ++g) {
    int j = n0 + wc * 64 + g * 16 + (l & 15);
    float bv = bias[j];
    #pragma unroll
    for (int f = 0; f < 4; ++f) {
      int row0 = m0 + wr * 64 + f * 16 + ((l >> 4) << 2);
      #pragma unroll
      for (int r = 0; r < 4; ++r)
        co[(long)(row0 + r) * N + j] = acc[f][g][r] + bv;
    }
  }
}

// ---------------- flash attention v7b (proven 76.5us) ----------------
__global__ __launch_bounds__(128, 2)
void mha_attn7(const _Float16* __restrict__ Q, const _Float16* __restrict__ K,
               const _Float16* __restrict__ Vt, const _Float16* __restrict__ mh,
               _Float16* __restrict__ out) {
  __shared__ _Float16 Ksh[2][4096];   // [64 keys][128B], content XOR-swizzled
  __shared__ _Float16 Vsh[2][4096];   // [64 d-rows][128B = 64 keys], XOR-swizzled
  const int t = threadIdx.x, l = t & 63, w = t >> 6;   // w in {0,1}
  const int hi = l >> 4, q = l & 15;

  const int bid = blockIdx.x;
  const int idx = bid >> 3;
  const int bh = (bid & 7) * 8 + (idx >> 4);
  const int qt = idx & 15;
  const int b = bh >> 4, h = bh & 15;
  const long base = (long)bh * (T_ * DH_);
  const int qb = qt * 128 + w * 64;

  half8 qf[4][2];
  #pragma unroll
  for (int G = 0; G < 4; ++G) {
    qf[G][0] = *(const half8*)(Q + base + (long)(qb + G * 16 + q) * DH_ + hi * 8);
    qf[G][1] = *(const half8*)(Q + base + (long)(qb + G * 16 + q) * DH_ + hi * 8 + 32);
  }

  const _Float16* ks[4];
  const _Float16* vs[4];
  #pragma unroll
  for (int j = 0; j < 4; ++j) {
    int c = w * 256 + j * 64 + l;
    int row = c >> 3, sub = c & 7;
    int s = (sub ^ ((row & 7) ^ ((row >> 2) & 7))) * 8;
    ks[j] = K  + base + row * DH_ + s;
    vs[j] = Vt + base + (long)row * T_ + s;
  }

  int kcb[4];
  #pragma unroll
  for (int g = 0; g < 4; ++g) {
    int kr = (g >> 1) * 32 + (q >> 2) * 8 + (g & 1) * 4 + (q & 3);
    int sw = (kr & 7) ^ ((kr >> 2) & 7);
    kcb[g] = kr * 128 + ((hi * 16) ^ (sw << 4));
  }
  int vcb[4];
  #pragma unroll
  for (int o = 0; o < 4; ++o) {
    int vr = o * 16 + q;
    int sw = (vr & 7) ^ ((vr >> 2) & 7);
    vcb[o] = vr * 128 + ((hi * 16) ^ (sw << 4));
  }

  const _Float16* mrow = mh + b * T_ + hi * 8;

  f32x4 acc[4][4], accD[4];
  #pragma unroll
  for (int G = 0; G < 4; ++G) {
    accD[G] = (f32x4){0.f, 0.f, 0.f, 0.f};
    #pragma unroll
    for (int o = 0; o < 4; ++o) acc[G][o] = (f32x4){0.f, 0.f, 0.f, 0.f};
  }

#define STAGEKV(BI, TT) do {                                                 \
    _Pragma("unroll")                                                        \
    for (int j = 0; j < 4; ++j) {                                            \
      gload_lds16(ks[j] + (TT) * (64 * DH_), &Ksh[BI][w * 2048 + j * 512]);  \
      gload_lds16(vs[j] + (TT) * 64,         &Vsh[BI][w * 2048 + j * 512]);  \
    }                                                                        \
  } while (0)

  STAGEKV(0, 0);
  __syncthreads();

  for (int kt = 0; kt < T_ / 64; ++kt) {
    const int bi = kt & 1;
    if (kt + 1 < T_ / 64) STAGEKV(bi ^ 1, kt + 1);

    const half8 mf0 = *(const half8*)(mrow + kt * 64);
    const half8 mf1 = *(const half8*)(mrow + kt * 64 + 32);

    const char* kbb = (const char*)Ksh[bi];
    const char* vbb = (const char*)Vsh[bi];
    half8 kf[4][2];
    #pragma unroll
    for (int g = 0; g < 4; ++g) {
      kf[g][0] = *(const half8*)(kbb + kcb[g]);
      kf[g][1] = *(const half8*)(kbb + (kcb[g] ^ 64));
    }
    half8 vf[4][2];
    #pragma unroll
    for (int o = 0; o < 4; ++o) {
      vf[o][0] = *(const half8*)(vbb + vcb[o]);
      vf[o][1] = *(const half8*)(vbb + (vcb[o] ^ 64));
    }

    #pragma unroll
    for (int G = 0; G < 4; ++G) {
      __builtin_amdgcn_s_setprio(1);
      f32x4 z[4];
      #pragma unroll
      for (int g = 0; g < 4; ++g) {
        f32x4 zz = (f32x4){0.f, 0.f, 0.f, 0.f};
        zz = MFMA16(kf[g][0], qf[G][0], zz);
        z[g] = MFMA16(kf[g][1], qf[G][1], zz);
      }
      __builtin_amdgcn_s_setprio(0);
      union { fp16x2 h2[4]; half8 h8; } u0, u1;
      #pragma unroll
      for (int i = 0; i < 2; ++i) {
        u0.h2[i]     = __builtin_amdgcn_cvt_pkrtz(__builtin_amdgcn_exp2f(z[0][2*i]),
                                                  __builtin_amdgcn_exp2f(z[0][2*i+1]));
        u0.h2[2 + i] = __builtin_amdgcn_cvt_pkrtz(__builtin_amdgcn_exp2f(z[1][2*i]),
                                                  __builtin_amdgcn_exp2f(z[1][2*i+1]));
        u1.h2[i]     = __builtin_amdgcn_cvt_pkrtz(__builtin_amdgcn_exp2f(z[2][2*i]),
                                                  __builtin_amdgcn_exp2f(z[2][2*i+1]));
        u1.h2[2 + i] = __builtin_amdgcn_cvt_pkrtz(__builtin_amdgcn_exp2f(z[3][2*i]),
                                                  __builtin_amdgcn_exp2f(z[3][2*i+1]));
      }
      __builtin_amdgcn_s_setprio(1);
      accD[G] = MFMA16(u0.h8, mf0, accD[G]);
      accD[G] = MFMA16(u1.h8, mf1, accD[G]);
      #pragma unroll
      for (int o = 0; o < 4; ++o) {
        acc[G][o] = MFMA16(u0.h8, vf[o][0], acc[G][o]);
        acc[G][o] = MFMA16(u1.h8, vf[o][1], acc[G][o]);
      }
      __builtin_amdgcn_s_setprio(0);
    }
    __syncthreads();
  }
#undef STAGEKV

  #pragma unroll
  for (int G = 0; G < 4; ++G)
    #pragma unroll
    for (int r = 0; r < 4; ++r) {
      float inv = __builtin_amdgcn_rcpf(accD[G][r]);
      int trow = qb + G * 16 + hi * 4 + r;
      #pragma unroll
      for (int o = 0; o < 4; ++o)
        out[((long)b * T_ + trow) * D_ + h * DH_ + o * 16 + q] =
            (_Float16)(acc[G][o][r] * inv);
    }
}

// ---------------- launch ----------------
extern "C" void kernel_launch(void* const* d_in, const int* in_sizes, int n_in,
                              void* d_out, int out_size, void* d_ws, size_t ws_size,
                              hipStream_t stream) {
  const float* x    = (const float*)d_in[0];
  const int*   mask = (const int*)d_in[1];
  const float* wqkv = (const float*)d_in[2];
  const float* bqkv = (const float*)d_in[3];
  const float* wout = (const float*)d_in[4];
  const float* bout = (const float*)d_in[5];
  float* out = (float*)d_out;

  _Float16* ws = (_Float16*)d_ws;
  const long nX = (long)B_ * T_ * D_;          // 8388608
  _Float16* xh    = ws;
  _Float16* wqkvt = xh + nX;                   // 3145728
  _Float16* woutt = wqkvt + (long)D_ * 3 * D_; // 1048576
  _Float16* mh    = woutt + (long)D_ * D_;     // 8192 halves
  _Float16* Qb    = woutt + (long)D_ * D_ + 16384;
  _Float16* Kb    = Qb + nX;
  _Float16* Vtg   = Kb + nX;                   // V transposed [bh][dh][t]
  _Float16* attnh = Vtg + nX;

  convert_f32_f16<<<2048, 256, 0, stream>>>(x, xh, nX);
  make_maskh<<<(B_ * T_) / 256, 256, 0, stream>>>(mask, mh, B_ * T_);
  transpose_f32_f16<<<dim3(3 * D_ / 32, D_ / 32), dim3(32, 8), 0, stream>>>(wqkv, wqkvt, D_, 3 * D_);
  transpose_f32_f16<<<dim3(D_ / 32, D_ / 32), dim3(32, 8), 0, stream>>>(wout, woutt, D_, D_);

  // qkv projection: 8-phase 256x256 GEMM, 384 blocks x 512 threads
  mha_gemm8<<<384, 512, 0, stream>>>(xh, wqkvt, bqkv, mh, Qb, Kb, Vtg);

  // attention: 1024 blocks x 128 threads (2 waves x 64 q-rows)
  mha_attn7<<<1024, 128, 0, stream>>>(Qb, Kb, Vtg, mh, attnh);

  // output projection: M=8192, N=1024, K=1024 (512 blocks, %8==0)
  mha_gemm_out<<<512, 256, 0, stream>>>(attnh, woutt, bout, out, B_ * T_, D_, D_, 8);
}

// Round 13
// 172.310 us; speedup vs baseline: 1.0467x; 1.0467x over previous
//
#include <hip/hip_runtime.h>
#include <hip/hip_bf16.h>
#include <stdint.h>

// Problem dims (fixed)
#define B_  4
#define T_  2048
#define D_  1024
#define H_  16
#define DH_ 64

typedef _Float16 half8 __attribute__((ext_vector_type(8)));
typedef _Float16 half4 __attribute__((ext_vector_type(4)));
typedef __fp16   fp16x2 __attribute__((ext_vector_type(2)));
typedef float    f32x4 __attribute__((ext_vector_type(4)));

#define MFMA16(a, b, c) __builtin_amdgcn_mfma_f32_16x16x32_f16(a, b, c, 0, 0, 0)

__device__ static inline void gload_lds16(const void* g, void* l) {
  __builtin_amdgcn_global_load_lds(
      (const __attribute__((address_space(1))) void*)g,
      (__attribute__((address_space(3))) void*)l, 16, 0, 0);
}

// ------------- fused prep: convert x, maskh, transpose wqkv, transpose wout -----
// One kernel, block-range partitioned (saves 3 launch gaps):
//   [0,2048)          : x f32 -> f16 (grid-stride, 4/thread)
//   [2048,5120)       : wqkv [1024][3072] f32 -> wqkvt [3072][1024] f16
//   [5120,6144)       : wout [1024][1024] f32 -> woutt [1024][1024]^T f16
//   [6144,6176)       : mask -> fp16 {0,1}
__global__ __launch_bounds__(256)
void prep_all(const float* __restrict__ x, const int* __restrict__ mask,
              const float* __restrict__ wqkv, const float* __restrict__ wout,
              _Float16* __restrict__ xh, _Float16* __restrict__ mh,
              _Float16* __restrict__ wqkvt, _Float16* __restrict__ woutt) {
  __shared__ float tile[32][33];
  const int bid = blockIdx.x, t = threadIdx.x;
  if (bid < 2048) {
    const long n = (long)B_ * T_ * D_;
    long i = ((long)bid * 256 + t) * 4;
    const long stride = (long)2048 * 256 * 4;
    for (; i < n; i += stride) {
      float4 v = *(const float4*)(x + i);
      half4 hv;
      hv.x = (_Float16)v.x; hv.y = (_Float16)v.y; hv.z = (_Float16)v.z; hv.w = (_Float16)v.w;
      *(half4*)(xh + i) = hv;
    }
  } else if (bid < 6144) {
    const float* in;
    _Float16* out;
    int n0, k0, N;
    if (bid < 5120) {
      int id = bid - 2048;
      in = wqkv; out = wqkvt; N = 3 * D_;
      n0 = (id % 96) * 32; k0 = (id / 96) * 32;
    } else {
      int id = bid - 5120;
      in = wout; out = woutt; N = D_;
      n0 = (id % 32) * 32; k0 = (id / 32) * 32;
    }
    const int xx = t & 31, y = t >> 5;   // 32 x 8
    #pragma unroll
    for (int j = 0; j < 32; j += 8)
      tile[y + j][xx] = in[(long)(k0 + y + j) * N + n0 + xx];
    __syncthreads();
    #pragma unroll
    for (int j = 0; j < 32; j += 8)
      out[(long)(n0 + y + j) * D_ + k0 + xx] = (_Float16)tile[xx][y + j];
  } else {
    int i = (bid - 6144) * 256 + t;
    mh[i] = mask[i] ? (_Float16)1.0f : (_Float16)0.0f;
  }
}

// ---------------- GEMM v2: C[M,N] = A[M,K] @ Bt[N,K]^T + bias ----------------
// 128x128 tile, BK=64, XOR-granule-swizzled LDS, bijective XCD swizzle.
// EPI 0: scatter Q (pre-scaled by 0.125*log2e) and K into [B,H,T,DH] fp16;
//        V tiles (n0>=2048) are transposed via LDS (coalesced [bh][dh][t]
//        16B stores) with masked keys zeroed (mhp).
// EPI 1: fp32 output + bias to co
template <int EPI>
__global__ __launch_bounds__(256, 2)
void mha_gemm2(const _Float16* __restrict__ A, const _Float16* __restrict__ Bt,
               const float* __restrict__ bias, const _Float16* __restrict__ mhp,
               _Float16* __restrict__ qo, _Float16* __restrict__ ko, _Float16* __restrict__ vo,
               float* __restrict__ co, int M, int N, int K, int gx) {
  __shared__ _Float16 shbuf[16384];       // As (8192) | Bs (8192); reused for V transpose
  _Float16* const As = shbuf;
  _Float16* const Bs = shbuf + 8192;
  const int t = threadIdx.x;
  const int l = t & 63;
  const int w = t >> 6;
  const int wr = w >> 1, wc = w & 1;

  const int cpx = gridDim.x >> 3;
  const int wg = (blockIdx.x & 7) * cpx + (blockIdx.x >> 3);
  const int m0 = (wg / gx) * 128, n0 = (wg % gx) * 128;

  const _Float16* ag[4];
  const _Float16* bg[4];
  #pragma unroll
  for (int j = 0; j < 4; ++j) {
    int c = j * 256 + t;
    int row = c >> 3, sub = c & 7;
    int s = (sub ^ (row & 7)) * 8;
    ag[j] = A  + (long)(m0 + row) * K + s;
    bg[j] = Bt + (long)(n0 + row) * K + s;
  }

  f32x4 acc[4][4];
  #pragma unroll
  for (int f = 0; f < 4; ++f)
    #pragma unroll
    for (int g = 0; g < 4; ++g) acc[f][g] = (f32x4){0.f, 0.f, 0.f, 0.f};

  const int hi = l >> 4;

  for (int k0 = 0; k0 < K; k0 += 64) {
    #pragma unroll
    for (int j = 0; j < 4; ++j) {
      gload_lds16(ag[j] + k0, &As[j * 2048 + w * 512]);
      gload_lds16(bg[j] + k0, &Bs[j * 2048 + w * 512]);
    }
    __syncthreads();
    half8 af[2][4], bf[2][4];
    #pragma unroll
    for (int kk = 0; kk < 2; ++kk)
      #pragma unroll
      for (int f = 0; f < 4; ++f) {
        int ra = wr * 64 + f * 16 + (l & 15);
        int rb = wc * 64 + f * 16 + (l & 15);
        af[kk][f] = *(const half8*)((const char*)As + ra * 128 +
                                    ((((kk << 2) | hi) ^ (ra & 7)) << 4));
        bf[kk][f] = *(const half8*)((const char*)Bs + rb * 128 +
                                    ((((kk << 2) | hi) ^ (rb & 7)) << 4));
      }
    #pragma unroll
    for (int kk = 0; kk < 2; ++kk)
      #pragma unroll
      for (int f = 0; f < 4; ++f)
        #pragma unroll
        for (int g = 0; g < 4; ++g)
          acc[f][g] = MFMA16(af[kk][f], bf[kk][g], acc[f][g]);
    __syncthreads();
  }

  if constexpr (EPI == 0) {
    if (n0 >= 2 * D_) {
      // ---- V tile: LDS transpose -> coalesced [bh][dh][t] 16B stores ----
      const int bb = m0 >> 11, m0t = m0 & 2047;
      #pragma unroll
      for (int g = 0; g < 4; ++g) {
        int colL = wc * 64 + g * 16 + (l & 15);      // local col 0..127
        float bv = bias[n0 + colL];
        int swz = (colL & 7) << 4;
        #pragma unroll
        for (int f = 0; f < 4; ++f) {
          int row0 = wr * 64 + f * 16 + hi * 4;      // local row base
          half4 hv;
          #pragma unroll
          for (int r = 0; r < 4; ++r) {
            float mv = (float)mhp[bb * T_ + m0t + row0 + r];
            hv[r] = (_Float16)((acc[f][g][r] + bv) * mv);
          }
          *(half4*)&shbuf[colL * 128 + (row0 ^ swz)] = hv;
        }
      }
      __syncthreads();
      #pragma unroll
      for (int i = 0; i < 8; ++i) {
        int e = i * 256 + t;
        int colL = e >> 4, chunk = e & 15;
        int swz = (colL & 7) << 4;
        half8 v8 = *(const half8*)&shbuf[colL * 128 + ((chunk * 8) ^ swz)];
        int d = (n0 + colL) & 1023;
        int h2 = d >> 6, dh = d & 63;
        *(half8*)&vo[(((long)bb * H_ + h2) * DH_ + dh) * T_ + m0t + chunk * 8] = v8;
      }
    } else {
      #pragma unroll
      for (int g = 0; g < 4; ++g) {
        int j = n0 + wc * 64 + g * 16 + (l & 15);
        float bv = bias[j];
        int which = j >> 10;          // uniform per block (0=Q, 1=K)
        int d = j & 1023;
        int h = d >> 6, dh = d & 63;
        _Float16* base = which == 0 ? qo : ko;
        float sc = which == 0 ? 0.1803368801f : 1.0f;   // 0.125 * log2(e) for Q
        #pragma unroll
        for (int f = 0; f < 4; ++f) {
          int row0 = m0 + wr * 64 + f * 16 + ((l >> 4) << 2);
          #pragma unroll
          for (int r = 0; r < 4; ++r) {
            int row = row0 + r;
            int bb = row >> 11, tt = row & 2047;
            base[(((long)bb * H_ + h) * T_ + tt) * DH_ + dh] =
                (_Float16)((acc[f][g][r] + bv) * sc);
          }
        }
      }
    }
  } else {
    #pragma unroll
    for (int g = 0; g < 4; ++g) {
      int j = n0 + wc * 64 + g * 16 + (l & 15);
      float bv = bias[j];
      #pragma unroll
      for (int f = 0; f < 4; ++f) {
        int row0 = m0 + wr * 64 + f * 16 + ((l >> 4) << 2);
        #pragma unroll
        for (int r = 0; r < 4; ++r)
          co[(long)(row0 + r) * N + j] = acc[f][g][r] + bv;
      }
    }
  }
}

// ---------------- flash attention v7b (proven 76.5us) ----------------
// 2 waves x 64 q-rows, 4 G-chains, 1024 blocks; K and V staged in LDS via
// global_load_lds dbuf one tile ahead, XOR-swizzled both-sides; T5 setprio
// around MFMA clusters. Masked-V numerator, denominator-by-MFMA, exp2-only.
__global__ __launch_bounds__(128, 2)
void mha_attn7(const _Float16* __restrict__ Q, const _Float16* __restrict__ K,
               const _Float16* __restrict__ Vt, const _Float16* __restrict__ mh,
               _Float16* __restrict__ out) {
  __shared__ _Float16 Ksh[2][4096];   // [64 keys][128B], content XOR-swizzled
  __shared__ _Float16 Vsh[2][4096];   // [64 d-rows][128B = 64 keys], XOR-swizzled
  const int t = threadIdx.x, l = t & 63, w = t >> 6;   // w in {0,1}
  const int hi = l >> 4, q = l & 15;

  const int bid = blockIdx.x;
  const int idx = bid >> 3;
  const int bh = (bid & 7) * 8 + (idx >> 4);
  const int qt = idx & 15;
  const int b = bh >> 4, h = bh & 15;
  const long base = (long)bh * (T_ * DH_);
  const int qb = qt * 128 + w * 64;

  half8 qf[4][2];
  #pragma unroll
  for (int G = 0; G < 4; ++G) {
    qf[G][0] = *(const half8*)(Q + base + (long)(qb + G * 16 + q) * DH_ + hi * 8);
    qf[G][1] = *(const half8*)(Q + base + (long)(qb + G * 16 + q) * DH_ + hi * 8 + 32);
  }

  const _Float16* ks[4];
  const _Float16* vs[4];
  #pragma unroll
  for (int j = 0; j < 4; ++j) {
    int c = w * 256 + j * 64 + l;
    int row = c >> 3, sub = c & 7;
    int s = (sub ^ ((row & 7) ^ ((row >> 2) & 7))) * 8;
    ks[j] = K  + base + row * DH_ + s;
    vs[j] = Vt + base + (long)row * T_ + s;
  }

  int kcb[4];
  #pragma unroll
  for (int g = 0; g < 4; ++g) {
    int kr = (g >> 1) * 32 + (q >> 2) * 8 + (g & 1) * 4 + (q & 3);
    int sw = (kr & 7) ^ ((kr >> 2) & 7);
    kcb[g] = kr * 128 + ((hi * 16) ^ (sw << 4));
  }
  int vcb[4];
  #pragma unroll
  for (int o = 0; o < 4; ++o) {
    int vr = o * 16 + q;
    int sw = (vr & 7) ^ ((vr >> 2) & 7);
    vcb[o] = vr * 128 + ((hi * 16) ^ (sw << 4));
  }

  const _Float16* mrow = mh + b * T_ + hi * 8;

  f32x4 acc[4][4], accD[4];
  #pragma unroll
  for (int G = 0; G < 4; ++G) {
    accD[G] = (f32x4){0.f, 0.f, 0.f, 0.f};
    #pragma unroll
    for (int o = 0; o < 4; ++o) acc[G][o] = (f32x4){0.f, 0.f, 0.f, 0.f};
  }

#define STAGEKV(BI, TT) do {                                                 \
    _Pragma("unroll")                                                        \
    for (int j = 0; j < 4; ++j) {                                            \
      gload_lds16(ks[j] + (TT) * (64 * DH_), &Ksh[BI][w * 2048 + j * 512]);  \
      gload_lds16(vs[j] + (TT) * 64,         &Vsh[BI][w * 2048 + j * 512]);  \
    }                                                                        \
  } while (0)

  STAGEKV(0, 0);
  __syncthreads();

  for (int kt = 0; kt < T_ / 64; ++kt) {
    const int bi = kt & 1;
    if (kt + 1 < T_ / 64) STAGEKV(bi ^ 1, kt + 1);

    const half8 mf0 = *(const half8*)(mrow + kt * 64);
    const half8 mf1 = *(const half8*)(mrow + kt * 64 + 32);

    const char* kbb = (const char*)Ksh[bi];
    const char* vbb = (const char*)Vsh[bi];
    half8 kf[4][2];
    #pragma unroll
    for (int g = 0; g < 4; ++g) {
      kf[g][0] = *(const half8*)(kbb + kcb[g]);
      kf[g][1] = *(const half8*)(kbb + (kcb[g] ^ 64));
    }
    half8 vf[4][2];
    #pragma unroll
    for (int o = 0; o < 4; ++o) {
      vf[o][0] = *(const half8*)(vbb + vcb[o]);
      vf[o][1] = *(const half8*)(vbb + (vcb[o] ^ 64));
    }

    #pragma unroll
    for (int G = 0; G < 4; ++G) {
      __builtin_amdgcn_s_setprio(1);
      f32x4 z[4];
      #pragma unroll
      for (int g = 0; g < 4; ++g) {
        f32x4 zz = (f32x4){0.f, 0.f, 0.f, 0.f};
        zz = MFMA16(kf[g][0], qf[G][0], zz);
        z[g] = MFMA16(kf[g][1], qf[G][1], zz);
      }
      __builtin_amdgcn_s_setprio(0);
      union { fp16x2 h2[4]; half8 h8; } u0, u1;
      #pragma unroll
      for (int i = 0; i < 2; ++i) {
        u0.h2[i]     = __builtin_amdgcn_cvt_pkrtz(__builtin_amdgcn_exp2f(z[0][2*i]),
                                                  __builtin_amdgcn_exp2f(z[0][2*i+1]));
        u0.h2[2 + i] = __builtin_amdgcn_cvt_pkrtz(__builtin_amdgcn_exp2f(z[1][2*i]),
                                                  __builtin_amdgcn_exp2f(z[1][2*i+1]));
        u1.h2[i]     = __builtin_amdgcn_cvt_pkrtz(__builtin_amdgcn_exp2f(z[2][2*i]),
                                                  __builtin_amdgcn_exp2f(z[2][2*i+1]));
        u1.h2[2 + i] = __builtin_amdgcn_cvt_pkrtz(__builtin_amdgcn_exp2f(z[3][2*i]),
                                                  __builtin_amdgcn_exp2f(z[3][2*i+1]));
      }
      __builtin_amdgcn_s_setprio(1);
      accD[G] = MFMA16(u0.h8, mf0, accD[G]);
      accD[G] = MFMA16(u1.h8, mf1, accD[G]);
      #pragma unroll
      for (int o = 0; o < 4; ++o) {
        acc[G][o] = MFMA16(u0.h8, vf[o][0], acc[G][o]);
        acc[G][o] = MFMA16(u1.h8, vf[o][1], acc[G][o]);
      }
      __builtin_amdgcn_s_setprio(0);
    }
    __syncthreads();
  }
#undef STAGEKV

  #pragma unroll
  for (int G = 0; G < 4; ++G)
    #pragma unroll
    for (int r = 0; r < 4; ++r) {
      float inv = __builtin_amdgcn_rcpf(accD[G][r]);
      int trow = qb + G * 16 + hi * 4 + r;
      #pragma unroll
      for (int o = 0; o < 4; ++o)
        out[((long)b * T_ + trow) * D_ + h * DH_ + o * 16 + q] =
            (_Float16)(acc[G][o][r] * inv);
    }
}

// ---------------- launch ----------------
extern "C" void kernel_launch(void* const* d_in, const int* in_sizes, int n_in,
                              void* d_out, int out_size, void* d_ws, size_t ws_size,
                              hipStream_t stream) {
  const float* x    = (const float*)d_in[0];
  const int*   mask = (const int*)d_in[1];
  const float* wqkv = (const float*)d_in[2];
  const float* bqkv = (const float*)d_in[3];
  const float* wout = (const float*)d_in[4];
  const float* bout = (const float*)d_in[5];
  float* out = (float*)d_out;

  _Float16* ws = (_Float16*)d_ws;
  const long nX = (long)B_ * T_ * D_;          // 8388608
  _Float16* xh    = ws;
  _Float16* wqkvt = xh + nX;                   // 3145728
  _Float16* woutt = wqkvt + (long)D_ * 3 * D_; // 1048576
  _Float16* mh    = woutt + (long)D_ * D_;     // 8192 halves
  _Float16* Qb    = woutt + (long)D_ * D_ + 16384;
  _Float16* Kb    = Qb + nX;
  _Float16* Vtg   = Kb + nX;                   // V transposed [bh][dh][t]
  _Float16* attnh = Vtg + nX;

  // fused prep: convert x + transpose wqkv + transpose wout + maskh
  prep_all<<<6176, 256, 0, stream>>>(x, mask, wqkv, wout, xh, mh, wqkvt, woutt);

  // qkv projection: M=8192, N=3072, K=1024 (1536 blocks, %8==0)
  // writes Q (scaled), K, and V transposed+masked (coalesced via LDS transpose)
  mha_gemm2<0><<<1536, 256, 0, stream>>>(
      xh, wqkvt, bqkv, mh, Qb, Kb, Vtg, nullptr, B_ * T_, 3 * D_, D_, 24);

  // attention: 1024 blocks x 128 threads (2 waves x 64 q-rows)
  mha_attn7<<<1024, 128, 0, stream>>>(Qb, Kb, Vtg, mh, attnh);

  // output projection: M=8192, N=1024, K=1024 (512 blocks, %8==0)
  mha_gemm2<1><<<512, 256, 0, stream>>>(
      attnh, woutt, bout, nullptr, nullptr, nullptr, nullptr, out, B_ * T_, D_, D_, 8);
}